// Round 7
// baseline (1086.290 us; speedup 1.0000x reference)
//
#include <hip/hip_runtime.h>
#include <math.h>

#define NB 64
#define S_ 432
#define D_ 512
#define C_ 128

typedef unsigned short ushort_t;
typedef unsigned int uint_t;
typedef __attribute__((ext_vector_type(8))) short short8;
typedef __attribute__((ext_vector_type(4))) float f32x4;

// ---- bf16 helpers (RNE) ----
__device__ inline ushort_t f2bf(float v) {
    uint_t x = __float_as_uint(v);
    x += 0x7fffu + ((x >> 16) & 1u);
    return (ushort_t)(x >> 16);
}
__device__ inline float bf2f(ushort_t b) { return __uint_as_float(((uint_t)b) << 16); }
__device__ inline void split2(float v, ushort_t& h, ushort_t& l) {
    h = f2bf(v);
    l = f2bf(v - bf2f(h));
}

// relu on an h/l fragment pair: x>0 iff hi sign bit clear (hi==+0 keeps l=x, correct)
__device__ inline void relu_frag(short8& h, short8& l) {
    uint_t* hp = (uint_t*)&h; uint_t* lp = (uint_t*)&l;
    #pragma unroll
    for (int i = 0; i < 4; ++i) {
        uint_t m = ((hp[i] & 0x8000u) ? 0xffffu : 0u)
                 | ((hp[i] & 0x80000000u) ? 0xffff0000u : 0u);
        hp[i] &= ~m; lp[i] &= ~m;
    }
}

// ---- fp32 -> (hi,lo) bf16 split arrays ----
__global__ __launch_bounds__(256)
void split_k(const float* __restrict__ src, ushort_t* __restrict__ dh,
             ushort_t* __restrict__ dl, long n4) {
    long i = (long)blockIdx.x * 256 + threadIdx.x;
    long stride = (long)gridDim.x * 256;
    for (; i < n4; i += stride) {
        float4 v = *(const float4*)&src[i * 4];
        ushort_t h0,l0,h1,l1,h2,l2,h3,l3;
        split2(v.x,h0,l0); split2(v.y,h1,l1); split2(v.z,h2,l2); split2(v.w,h3,l3);
        uint2 ph, pl;
        ph.x = (uint_t)h0 | ((uint_t)h1 << 16); ph.y = (uint_t)h2 | ((uint_t)h3 << 16);
        pl.x = (uint_t)l0 | ((uint_t)l1 << 16); pl.y = (uint_t)l2 | ((uint_t)l3 << 16);
        *(uint2*)&dh[i * 4] = ph; *(uint2*)&dl[i * 4] = pl;
    }
}

// zero the 64-byte OOB-redirect granule (d_ws is poisoned every launch)
__global__ void zero64_k(ushort_t* z) { z[threadIdx.x] = 0; }

// ---------------------------------------------------------------------------
// Split-bf16 MFMA GEMM, global_load_lds staging: C[m,n]=epi(sum_k A[m,k]*Bg[n,k])
// A,Bg as separate hi/lo ushort arrays, k-contig rows (Bg = B^T, or B if symm).
// acc += Ah*Bh + Ah*Bl + Al*Bh. Tile 128x128, 4 waves (2x2), 4x4 frags 16x16x32.
// LDS: 4 tiles [128][32] ushort = 32 KB, staged by global_load_lds width=16
// (wave w stages tile w; linear LDS dest). Bank swizzle via PRE-SWIZZLED global
// source: 16B granule c stored at physical chunk p = c ^ ((row>>1)&3); ds_read
// uses the same XOR -> 2-way conflicts only (free).
// K tail (K%32==16): OOB granules redirected to 64B zero scratch (zbuf).
// XCD decode: xcd=bid&7 -> batches z%8==xcd; same-batch tiles share an XCD L2.
// F: 0 none | 1 0.5*(3I-acc) | 2 cov dual-out | 4 *e0[n]+e1[n]
//  | 5 *sqrt(trc/128)/16 | 6 +e0[m].  WS: h/l out. WF: fp32 out.
// Edge: m0=min(bx*128,M-128) -> overlapped blocks write identical bits.
// ---------------------------------------------------------------------------
template<int F, bool RELU, bool WS, bool WF>
__global__ __launch_bounds__(256)
void gemm_hl(const ushort_t* __restrict__ Agh, const ushort_t* __restrict__ Agl,
             const ushort_t* __restrict__ Bgh, const ushort_t* __restrict__ Bgl,
             ushort_t* __restrict__ Ch, ushort_t* __restrict__ Cl,
             ushort_t* __restrict__ C2h, ushort_t* __restrict__ C2l,
             float* __restrict__ Cf,
             int M, int N, int K, int lda, int ldb, int ldc,
             long sA, long sB, long sC,
             const float* __restrict__ e0, const float* __restrict__ e1,
             const float* __restrict__ trc, const float* __restrict__ mu,
             const ushort_t* __restrict__ zbuf, int mtl, int tpbl)
{
    __shared__ __align__(16) ushort_t lds[4][128][32];   // 32 KB exactly

    const int tid = threadIdx.x;
    const int lid = blockIdx.x;
    const int xcd = lid & 7, idx = lid >> 3;
    const int zb = xcd + ((idx >> tpbl) << 3);
    const int t  = idx & ((1 << tpbl) - 1);
    const int bx = t & ((1 << mtl) - 1), by = t >> mtl;
    int m0 = bx << 7; if (m0 > M - 128) m0 = M - 128;
    int n0 = by << 7; if (n0 > N - 128) n0 = N - 128;

    const int wv = tid >> 6, ln = tid & 63;
    const int wr = wv >> 1, wc = wv & 1;
    const int lm = ln & 15, kg = ln >> 4;

    // staging role: wave wv fills tile wv (0=Ah,1=Al,2=Bh,3=Bl)
    const ushort_t* gsrc;
    if      (wv == 0) gsrc = Agh + (long)zb * sA;
    else if (wv == 1) gsrc = Agl + (long)zb * sA;
    else if (wv == 2) gsrc = Bgh + (long)zb * sB;
    else              gsrc = Bgl + (long)zb * sB;
    const int grow0 = (wv < 2) ? m0 : n0;
    const int gld   = (wv < 2) ? lda : ldb;
    const int srow  = ln >> 2;       // 0..15 row within 16-row group
    const int sp    = ln & 3;        // physical 16B chunk

    f32x4 acc[4][4];
    #pragma unroll
    for (int i = 0; i < 4; ++i)
        #pragma unroll
        for (int j = 0; j < 4; ++j)
            acc[i][j] = (f32x4){0.f, 0.f, 0.f, 0.f};

    const int pA = kg ^ ((lm >> 1) & 3);   // swizzled read chunk (lane-const)

    for (int k0 = 0; k0 < K; k0 += 32) {
        // ---- stage this wave's tile: 8 x global_load_lds (1 KB each) ----
        #pragma unroll
        for (int i = 0; i < 8; ++i) {
            int row = i * 16 + srow;
            int c = sp ^ ((row >> 1) & 3);                 // logical granule
            const ushort_t* src = gsrc + (long)(grow0 + row) * gld + k0 + c * 8;
            if (k0 + c * 8 >= K) src = zbuf;               // K-tail -> zeros
            __builtin_amdgcn_global_load_lds(
                (const __attribute__((address_space(1))) void*)src,
                (__attribute__((address_space(3))) void*)&lds[wv][i * 16][0],
                16, 0, 0);
        }
        __syncthreads();   // drains vmcnt -> LDS visible to all waves

        // ---- compute ----
        short8 ah[4], al[4];
        #pragma unroll
        for (int f = 0; f < 4; ++f) {
            int row = wr * 64 + f * 16 + lm;
            ah[f] = *(const short8*)&lds[0][row][pA * 8];
            al[f] = *(const short8*)&lds[1][row][pA * 8];
            if (RELU) relu_frag(ah[f], al[f]);
        }
        #pragma unroll
        for (int fn = 0; fn < 4; ++fn) {
            int row = wc * 64 + fn * 16 + lm;
            short8 bh = *(const short8*)&lds[2][row][pA * 8];
            short8 bl = *(const short8*)&lds[3][row][pA * 8];
            #pragma unroll
            for (int fm = 0; fm < 4; ++fm) {
                acc[fm][fn] = __builtin_amdgcn_mfma_f32_16x16x32_bf16(ah[fm], bh, acc[fm][fn], 0, 0, 0);
                acc[fm][fn] = __builtin_amdgcn_mfma_f32_16x16x32_bf16(ah[fm], bl, acc[fm][fn], 0, 0, 0);
                acc[fm][fn] = __builtin_amdgcn_mfma_f32_16x16x32_bf16(al[fm], bh, acc[fm][fn], 0, 0, 0);
            }
        }
        __syncthreads();   // protect LDS before next stage
    }

    // ---- epilogue ----  C/D map (m89): col = lane&15, row = (lane>>4)*4 + reg
    const int rg = kg * 4;
    float fscale = 1.f, invtr = 1.f;
    if (F == 5) fscale = sqrtf(trc[zb] * (1.0f / 128.0f)) * 0.0625f;
    if (F == 2) invtr = 1.0f / trc[zb];

    #pragma unroll
    for (int fm = 0; fm < 4; ++fm) {
        #pragma unroll
        for (int r = 0; r < 4; ++r) {
            int gm = m0 + wr * 64 + fm * 16 + rg + r;
            float mum = 0.f;
            if (F == 2) mum = mu[(long)zb * S_ + gm];
            #pragma unroll
            for (int fn = 0; fn < 4; ++fn) {
                int gn = n0 + wc * 64 + fn * 16 + lm;
                float v = acc[fm][fn][r];
                long o = (long)zb * sC + (long)gm * ldc + gn;
                if (F == 2) {
                    float ahv = (v - 128.0f * mum * mu[(long)zb * S_ + gn]) * invtr;
                    ushort_t h, l; split2(ahv, h, l);
                    Ch[o] = h; Cl[o] = l;
                    float z0 = ((gm == gn) ? 1.5f : 0.0f) - 0.5f * ahv;
                    split2(z0, h, l);
                    C2h[o] = h; C2l[o] = l;
                } else {
                    if (F == 1)      v = ((gm == gn) ? 1.5f : 0.0f) - 0.5f * v;
                    else if (F == 4) v = v * e0[gn] + e1[gn];
                    else if (F == 5) v *= fscale;
                    else if (F == 6) v += e0[gm];
                    if (WF) Cf[o] = v;
                    if (WS) { ushort_t h, l; split2(v, h, l); Ch[o] = h; Cl[o] = l; }
                }
            }
        }
    }
}

// ---- BN fold: feat = acc*sc[c] + sh[c] ----
__global__ void bnfold_k(const float* __restrict__ bc, const float* __restrict__ gamma,
                         const float* __restrict__ beta, const float* __restrict__ mean,
                         const float* __restrict__ var, float* __restrict__ sc,
                         float* __restrict__ sh)
{
    int c = threadIdx.x;
    float s = gamma[c] / sqrtf(var[c] + 1e-5f);
    sc[c] = s;
    sh[c] = beta[c] + (bc[c] - mean[c]) * s;
}

// ---- per-row channel mean + trace contribution (one wave per feat row) ----
__global__ __launch_bounds__(256)
void mu_rowq_bf(const ushort_t* __restrict__ fh, const ushort_t* __restrict__ fl,
                float* __restrict__ mu, float* __restrict__ rowq)
{
    int row  = blockIdx.x * 4 + (threadIdx.x >> 6);
    int lane = threadIdx.x & 63;
    uint_t h = *(const uint_t*)&fh[(long)row * C_ + lane * 2];
    uint_t l = *(const uint_t*)&fl[(long)row * C_ + lane * 2];
    float f0 = bf2f((ushort_t)(h & 0xffffu)) + bf2f((ushort_t)(l & 0xffffu));
    float f1 = bf2f((ushort_t)(h >> 16)) + bf2f((ushort_t)(l >> 16));
    float sum = f0 + f1;
    float sq  = f0 * f0 + f1 * f1;
    #pragma unroll
    for (int off = 32; off; off >>= 1) {
        sum += __shfl_xor(sum, off);
        sq  += __shfl_xor(sq, off);
    }
    if (lane == 0) {
        float m = sum * (1.0f / 128.0f);
        mu[row]   = m;
        rowq[row] = sq - 128.0f * m * m;   // sum_s rowq = 128*trace(cov) = trc
    }
}

__global__ __launch_bounds__(256)
void trace_red_k(const float* __restrict__ rowq, float* __restrict__ trc)
{
    int b = blockIdx.x, tid = threadIdx.x;
    float v = 0.f;
    for (int s = tid; s < S_; s += 256) v += rowq[(long)b * S_ + s];
    __shared__ float red[256];
    red[tid] = v; __syncthreads();
    if (tid < 128) red[tid] += red[tid + 128];
    __syncthreads();
    if (tid < 64) {
        float r = red[tid] + red[tid + 64];
        #pragma unroll
        for (int off = 32; off; off >>= 1) r += __shfl_xor(r, off);
        if (tid == 0) trc[b] = r;
    }
}

// ---- row softmax (len 432) on h/l logits, one wave/row, h/l out ----
__global__ __launch_bounds__(256)
void softmax_split_k(const ushort_t* __restrict__ ph, const ushort_t* __restrict__ pl,
                     ushort_t* __restrict__ ah, ushort_t* __restrict__ al)
{
    int row  = blockIdx.x * 4 + (threadIdx.x >> 6);
    int lane = threadIdx.x & 63;
    float vals[7];
    float mx = -3.0e38f;
    #pragma unroll
    for (int i = 0; i < 7; ++i) {
        int c = lane + i * 64;
        vals[i] = (c < S_) ? (bf2f(ph[(long)row * S_ + c]) + bf2f(pl[(long)row * S_ + c]))
                           : -3.0e38f;
        mx = fmaxf(mx, vals[i]);
    }
    #pragma unroll
    for (int off = 32; off; off >>= 1) mx = fmaxf(mx, __shfl_xor(mx, off));
    float sum = 0.f;
    #pragma unroll
    for (int i = 0; i < 7; ++i) { vals[i] = __expf(vals[i] - mx); sum += vals[i]; }
    #pragma unroll
    for (int off = 32; off; off >>= 1) sum += __shfl_xor(sum, off);
    float inv = 1.0f / sum;
    #pragma unroll
    for (int i = 0; i < 7; ++i) {
        int c = lane + i * 64;
        if (c < S_) {
            ushort_t h, l; split2(vals[i] * inv, h, l);
            ah[(long)row * S_ + c] = h;
            al[(long)row * S_ + c] = l;
        }
    }
}

extern "C" void kernel_launch(void* const* d_in, const int* in_sizes, int n_in,
                              void* d_out, int out_size, void* d_ws, size_t ws_size,
                              hipStream_t stream)
{
    (void)in_sizes; (void)n_in; (void)out_size;
    const float* x     = (const float*)d_in[0];
    // d_in[1] = mask (all true) -- no-op in the reference math
    const float* Wv    = (const float*)d_in[2];
    const float* bv    = (const float*)d_in[3];
    const float* Wc    = (const float*)d_in[4];
    const float* bc    = (const float*)d_in[5];
    const float* gamma = (const float*)d_in[6];
    const float* beta  = (const float*)d_in[7];
    const float* mean  = (const float*)d_in[8];
    const float* var   = (const float*)d_in[9];
    float* out = (float*)d_out;

    const long SS  = (long)S_ * S_;        // 186624
    const long XSZ = (long)NB * S_ * D_;   // 14155776
    const long FSZ = (long)NB * S_ * C_;
    const long sXD = (long)S_ * D_;
    const long sFC = (long)S_ * C_;

    // adaptive chunk: 64 batches if workspace allows (needs ~264 MB), else 32
    const long need64 = 2L*XSZ*2 + 2L*FSZ*2 + 8L*64*SS*2 + (2L<<20)
                      + (long)NB*S_*8 + 65536;
    const int HBr = (ws_size >= (size_t)need64) ? 64 : 32;

    char* p = (char*)d_ws;
    auto alloc = [&](long bytes) { char* r = p; p += (bytes + 255) & ~255L; return r; };

    // x splits live in d_out (exact fit; dead before final output writes)
    ushort_t* xh = (ushort_t*)d_out;
    ushort_t* xl = xh + XSZ;

    ushort_t* vTh = (ushort_t*)alloc(XSZ * 2);   // v^T per batch: (D, S)
    ushort_t* vTl = (ushort_t*)alloc(XSZ * 2);
    ushort_t* fth = (ushort_t*)alloc(FSZ * 2);
    ushort_t* ftl = (ushort_t*)alloc(FSZ * 2);
    ushort_t *Sh[4], *Sl[4];
    for (int i = 0; i < 4; ++i) {
        Sh[i] = (ushort_t*)alloc((long)HBr * SS * 2);
        Sl[i] = (ushort_t*)alloc((long)HBr * SS * 2);
    }
    ushort_t* Wvh = (ushort_t*)alloc(512L * 512 * 2);
    ushort_t* Wvl = (ushort_t*)alloc(512L * 512 * 2);
    ushort_t* Wch = (ushort_t*)alloc(128L * 512 * 2);
    ushort_t* Wcl = (ushort_t*)alloc(128L * 512 * 2);
    float* mu   = (float*)alloc((long)NB * S_ * 4);
    float* rowq = (float*)alloc((long)NB * S_ * 4);
    float* trc  = (float*)alloc(256);
    float* sc   = (float*)alloc(512);
    float* shv  = (float*)alloc(512);
    ushort_t* zbuf = (ushort_t*)alloc(256);      // zeroed 64B granule (+slack)

    const float* nil = nullptr;
    ushort_t* nus = nullptr;
    dim3 blk(256);

    // 0) zero scratch granule, BN fold, input splits (x into d_out)
    zero64_k<<<1, 64, 0, stream>>>(zbuf);
    bnfold_k<<<1, 128, 0, stream>>>(bc, gamma, beta, mean, var, sc, shv);
    split_k<<<2048, blk, 0, stream>>>(x,  xh,  xl,  XSZ / 4);
    split_k<<<256,  blk, 0, stream>>>(Wv, Wvh, Wvl, (512L * 512) / 4);
    split_k<<<64,   blk, 0, stream>>>(Wc, Wch, Wcl, (128L * 512) / 4);

    // 1) v^T = Wv @ x^T + bv (row bias): M=D, N=S, K=512; 16 tiles/batch
    gemm_hl<6, false, true, false><<<dim3(16 * NB), blk, 0, stream>>>(
        Wvh, Wvl, xh, xl, vTh, vTl, nus, nus, nullptr,
        D_, S_, D_, D_, D_, S_, 0, sXD, sXD, bv, nil, nil, nil, zbuf, 2, 4);

    // 2) feat = BN(relu(x)@Wc^T + bc): M=S, N=C, K=512; 4 tiles/batch
    gemm_hl<4, true, true, false><<<dim3(4 * NB), blk, 0, stream>>>(
        xh, xl, Wch, Wcl, fth, ftl, nus, nus, nullptr,
        S_, C_, D_, D_, D_, C_, sXD, 0, sFC, sc, shv, nil, nil, zbuf, 2, 2);

    // 3) mu / trace (all batches)
    mu_rowq_bf<<<dim3(NB * S_ / 4), blk, 0, stream>>>(fth, ftl, mu, rowq);
    trace_red_k<<<dim3(NB), blk, 0, stream>>>(rowq, trc);

    // 4) per-chunk: cov -> NS -> logits -> softmax -> attn@v
    for (int b0 = 0; b0 < NB; b0 += HBr) {
        const ushort_t* fch = fth + (long)b0 * sFC;
        const ushort_t* fcl = ftl + (long)b0 * sFC;
        const float* trcC = trc + b0;
        const float* muC  = mu + (long)b0 * S_;
        dim3 gS(16 * HBr);

        // cov -> Ah (S0) and ZY0 (S1), both symmetric; K=128 no tail
        gemm_hl<2, false, false, false><<<gS, blk, 0, stream>>>(
            fch, fcl, fch, fcl, Sh[0], Sl[0], Sh[1], Sl[1], nullptr,
            S_, S_, C_, C_, C_, S_, sFC, sFC, SS, nil, nil, trcC, muC, zbuf, 2, 4);

        // Newton-Schulz (iterN=5); symmetric operands -> straight splits both sides
        #define NSG(Fv, AH, AL, BH, BL, CH, CL) \
            gemm_hl<Fv, false, true, false><<<gS, blk, 0, stream>>>( \
                AH, AL, BH, BL, CH, CL, nus, nus, nullptr, \
                S_, S_, S_, S_, S_, S_, SS, SS, SS, nil, nil, nil, nil, zbuf, 2, 4)

        NSG(0, Sh[0], Sl[0], Sh[1], Sl[1], Sh[2], Sl[2]);  // Y1 = Ah@Z0        -> S2
        NSG(1, Sh[1], Sl[1], Sh[2], Sl[2], Sh[3], Sl[3]);  // T1 = .5(3I-Z0@Y1) -> S3
        NSG(0, Sh[2], Sl[2], Sh[3], Sl[3], Sh[0], Sl[0]);  // Y2 = Y1@T1        -> S0
        NSG(0, Sh[3], Sl[3], Sh[1], Sl[1], Sh[2], Sl[2]);  // Z2 = T1@Z0        -> S2
        NSG(1, Sh[2], Sl[2], Sh[0], Sl[0], Sh[1], Sl[1]);  // T2 = .5(3I-Z2@Y2) -> S1
        NSG(0, Sh[0], Sl[0], Sh[1], Sl[1], Sh[3], Sl[3]);  // Y3 = Y2@T2        -> S3
        NSG(0, Sh[1], Sl[1], Sh[2], Sl[2], Sh[0], Sl[0]);  // Z3 = T2@Z2        -> S0
        NSG(1, Sh[0], Sl[0], Sh[3], Sl[3], Sh[2], Sl[2]);  // T3 = .5(3I-Z3@Y3) -> S2
        NSG(0, Sh[3], Sl[3], Sh[2], Sl[2], Sh[1], Sl[1]);  // Y4 = Y3@T3        -> S1
        NSG(0, Sh[2], Sl[2], Sh[0], Sl[0], Sh[3], Sl[3]);  // Z4 = T3@Z3        -> S3
        NSG(1, Sh[3], Sl[3], Sh[1], Sl[1], Sh[0], Sl[0]);  // T4 = .5(3I-Z4@Y4) -> S0
        #undef NSG

        // logits = (Y4@T4) * sqrt(trc/128)/16 -> splits into S2
        gemm_hl<5, false, true, false><<<gS, blk, 0, stream>>>(
            Sh[1], Sl[1], Sh[0], Sl[0], Sh[2], Sl[2], nus, nus, nullptr,
            S_, S_, S_, S_, S_, S_, SS, SS, SS, nil, nil, trcC, nil, zbuf, 2, 4);

        // softmax -> attn splits into S3
        softmax_split_k<<<dim3(HBr * S_ / 4), blk, 0, stream>>>(
            Sh[2], Sl[2], Sh[3], Sl[3]);

        // out = attn @ v (Bg = v^T splits), fp32 into d_out (x splits dead now)
        gemm_hl<0, false, false, true><<<gS, blk, 0, stream>>>(
            Sh[3], Sl[3], vTh + (long)b0 * sXD, vTl + (long)b0 * sXD,
            nus, nus, nus, nus, out + (long)b0 * sXD,
            S_, D_, S_, S_, S_, D_, SS, sXD, sXD, nil, nil, nil, nil, zbuf, 2, 4);
    }
}